// Round 14
// baseline (401.441 us; speedup 1.0000x reference)
//
#include <hip/hip_runtime.h>
#include <stdint.h>

// PAM_Module: B=8, C=512, H=W=64 -> N=4096, O=64. Dtype auto-detected (bf16 vs fp32).
// out = gamma * (vw @ (xf @ att^T) + vb) + x   (softmax rows sum to 1 => vb passes through)
// MFMA pipeline:
//   K0 detect, K1 prep (wt/bcat/vbf/gf fp32 + vw->bf16 vwb),
//   K2 proj -> Qb,Kb bf16 [b][n][64] (fp32 path also writes xbf; bf16 aliases x),
//   K3 attn_mfma: single-pass shifted-exp softmax + PV + fused vw-GEMM epilogue.
//
// R14 = R13 (tall-i, 253us attn) with PV switched to v_mfma_f32_32x32x16_bf16:
// 2x FLOPs per instruction AND per 8-elem fragment (32768 vs 16384), ~15% higher
// ceiling (m119). PV MFMA instrs halve (64->32/iter/wave), af/pb load instrs
// halve per FLOP. acc = 4 x f32x16 (same 64 AGPRs). D layout (m74/m101):
// c-row = (reg&3)+8*(reg>>2)+4*(lane>>5), i-col = lane&31. QK^T/softmax/staging
// unchanged.
// ws: flag@0 gf@16 bcat@32 vbf@544 wt@2592 Qb@264736 Kb@4459040 vwb@8653344
//     xbf@9177632  (total 42,732,064 B)

#define B_ 8
#define C_ 512
#define N_ 4096

typedef unsigned short u16;
typedef unsigned int u32;
typedef __attribute__((ext_vector_type(8))) short bf16x8;
typedef __attribute__((ext_vector_type(4))) float f32x4;
typedef __attribute__((ext_vector_type(16))) float f32x16;

static __device__ __forceinline__ float b2f(u16 u) {
    return __uint_as_float(((u32)u) << 16);
}
static __device__ __forceinline__ u16 f2b(float f) {
    u32 u = __float_as_uint(f);
    u = u + 0x7fffu + ((u >> 16) & 1u);   // RNE
    return (u16)(u >> 16);
}
static __device__ __forceinline__ float ldf(const void* p, size_t i, int fl) {
    return fl ? b2f(((const u16*)p)[i]) : ((const float*)p)[i];
}
static __device__ __forceinline__ void glds16(const void* g, void* l) {
    __builtin_amdgcn_global_load_lds(
        (const __attribute__((address_space(1))) unsigned int*)g,
        (__attribute__((address_space(3))) unsigned int*)l, 16, 0, 0);
}

// ---------------- kernel 0: dtype detector ----------------------------------------
__global__ void detect_dtype(const u16* __restrict__ x, int* __restrict__ flag) {
    __shared__ int cnt[256];
    int t = threadIdx.x;
    int c = 0;
    for (int i = t; i < 4096; i += 256) {
        int e = (x[i] >> 7) & 0xFF;
        if (e >= 95 && e <= 140) c++;
    }
    cnt[t] = c;
    __syncthreads();
    for (int s = 128; s > 0; s >>= 1) {
        if (t < s) cnt[t] += cnt[t + s];
        __syncthreads();
    }
    if (t == 0) *flag = (cnt[0] >= 3686) ? 1 : 0;   // 1 = bf16, 0 = fp32
}

// ---------------- kernel 1: params -> fp32 ws, vw -> bf16 --------------------------
__global__ void prep_params(const void* __restrict__ qw, const void* __restrict__ qb,
                            const void* __restrict__ kw, const void* __restrict__ kb,
                            const void* __restrict__ vb, const void* __restrict__ gm,
                            const void* __restrict__ vw, const int* __restrict__ flagp,
                            float* __restrict__ wt, float* __restrict__ bcat,
                            float* __restrict__ vbf, float* __restrict__ gf,
                            u16* __restrict__ vwb) {
    int fl = *flagp;
    int gid = blockIdx.x * 256 + threadIdx.x;   // grid 256*256 = 65536
    if (gid < C_ * 128) {
        int c = gid >> 7, o = gid & 127;
        wt[c * 128 + o] = (o < 64) ? ldf(qw, (size_t)o * C_ + c, fl)
                                   : ldf(kw, (size_t)(o - 64) * C_ + c, fl);
    }
    if (gid < 128) bcat[gid] = (gid < 64) ? ldf(qb, gid, fl) : ldf(kb, gid - 64, fl);
    if (gid < C_) vbf[gid] = ldf(vb, gid, fl);
    if (gid == 0) gf[0] = ldf(gm, 0, fl);
    {   // vw -> bf16: 65536 threads x 4 elems = 262144 = C*C
        int v0 = gid * 4;
        ushort4 h;
        h.x = f2b(ldf(vw, v0 + 0, fl));
        h.y = f2b(ldf(vw, v0 + 1, fl));
        h.z = f2b(ldf(vw, v0 + 2, fl));
        h.w = f2b(ldf(vw, v0 + 3, fl));
        *(ushort4*)(vwb + v0) = h;
    }
}

// ---------------- kernel 2: Q/K projection -> bf16, grid (2, 64, 8) ---------------
// fp32 input: og==0 blocks also emit x as bf16 into xbf (fused xconv).
__global__ __launch_bounds__(256) void proj_qk(
        const void* __restrict__ xin, const int* __restrict__ flagp,
        const float* __restrict__ wt, const float* __restrict__ bcat,
        u16* __restrict__ Qb, u16* __restrict__ Kb, u16* __restrict__ xbf) {
    __shared__ __align__(16) char smem[32768];
    float* xs  = (float*)smem;            // [64][64]
    float* wsh = (float*)(smem + 16384);  // [64][64]
    const u16*   xb = (const u16*)xin;
    const float* xf = (const float*)xin;
    int fl = *flagp;

    int t = threadIdx.x;
    int og = blockIdx.x;
    int n0 = blockIdx.y * 64;
    int b  = blockIdx.z;
    int oc0 = og * 64;
    int tn = t & 15, to = t >> 4;

    float acc[4][4];
#pragma unroll
    for (int i = 0; i < 4; ++i)
#pragma unroll
        for (int j = 0; j < 4; ++j) acc[i][j] = 0.f;

    for (int c0 = 0; c0 < C_; c0 += 64) {
        __syncthreads();
        if (fl) {
#pragma unroll
            for (int rep = 0; rep < 4; ++rep) {
                int idx4 = rep * 256 + t;
                int cc = idx4 >> 4;
                int nn4 = (idx4 & 15) << 2;
                ushort4 uv = *(const ushort4*)(xb + ((size_t)(b * C_ + c0 + cc)) * N_ + n0 + nn4);
                float4 f;
                f.x = b2f(uv.x); f.y = b2f(uv.y); f.z = b2f(uv.z); f.w = b2f(uv.w);
                *(float4*)(xs + cc * 64 + nn4) = f;
            }
        } else {
#pragma unroll
            for (int rep = 0; rep < 4; ++rep) {
                int idx4 = rep * 256 + t;
                int cc = idx4 >> 4;
                int nn4 = (idx4 & 15) << 2;
                float4 v = *(const float4*)(xf + ((size_t)(b * C_ + c0 + cc)) * N_ + n0 + nn4);
                *(float4*)(xs + cc * 64 + nn4) = v;
                if (og == 0) {   // fused x -> bf16 (each (b,c,n) written exactly once)
                    ushort4 h;
                    h.x = f2b(v.x); h.y = f2b(v.y); h.z = f2b(v.z); h.w = f2b(v.w);
                    *(ushort4*)(xbf + ((size_t)(b * C_ + c0 + cc)) * N_ + n0 + nn4) = h;
                }
            }
        }
#pragma unroll
        for (int rep = 0; rep < 4; ++rep) {
            int idx4 = rep * 256 + t;
            int cc = idx4 >> 4;
            int oo4 = (idx4 & 15) << 2;
            *(float4*)(wsh + cc * 64 + oo4) =
                *(const float4*)(wt + (size_t)(c0 + cc) * 128 + oc0 + oo4);
        }
        __syncthreads();
#pragma unroll 8
        for (int cc = 0; cc < 64; ++cc) {
            float4 xa = *(const float4*)(xs + cc * 64 + (tn << 2));
            float4 wa = *(const float4*)(wsh + cc * 64 + (to << 2));
            acc[0][0] += xa.x * wa.x; acc[0][1] += xa.x * wa.y;
            acc[0][2] += xa.x * wa.z; acc[0][3] += xa.x * wa.w;
            acc[1][0] += xa.y * wa.x; acc[1][1] += xa.y * wa.y;
            acc[1][2] += xa.y * wa.z; acc[1][3] += xa.y * wa.w;
            acc[2][0] += xa.z * wa.x; acc[2][1] += xa.z * wa.y;
            acc[2][2] += xa.z * wa.z; acc[2][3] += xa.z * wa.w;
            acc[3][0] += xa.w * wa.x; acc[3][1] += xa.w * wa.y;
            acc[3][2] += xa.w * wa.z; acc[3][3] += xa.w * wa.w;
        }
    }

    float b0 = bcat[oc0 + (to << 2) + 0];
    float b1 = bcat[oc0 + (to << 2) + 1];
    float b2 = bcat[oc0 + (to << 2) + 2];
    float b3 = bcat[oc0 + (to << 2) + 3];
    u16* dst = (og == 0) ? Qb : Kb;
#pragma unroll
    for (int i = 0; i < 4; ++i) {
        int n = n0 + (tn << 2) + i;
        ushort4 h;
        h.x = f2b(acc[i][0] + b0); h.y = f2b(acc[i][1] + b1);
        h.z = f2b(acc[i][2] + b2); h.w = f2b(acc[i][3] + b3);
        *(ushort4*)(dst + ((size_t)b * N_ + n) * 64 + (to << 2)) = h;
    }
}

// ---------------- kernel 3: MFMA single-pass attention + fused vw epilogue --------
// grid (32, 8) remapped XCD-bijectively, 1024 threads (16 waves), 1 block/CU.
// Block: i-rows [i0, i0+128). Wave w: p_compute tile (rt=w&7 -> 16 i-rows,
// h2=w>>3 -> 64-j half of the 128-j tile); PV/epilogue c-slice [32w, 32w+32).
// PV uses mfma_32x32x16: A = x[c=lane&31][k=8*(lane>>5)+e],
// B = P[i=lane&31][j=8*(lane>>5)+e] (from Ps), D c-row=(reg&3)+8*(reg>>2)+4*(lane>>5).
// K LDS linear [128][64]u16, 16B-granule XOR swizzle (rule #21).
// LDS layout (byte offsets):
#define KSA_OFF  0        // K buf A [128][64]u16   16384 B (swizzled)
#define KSB_OFF  16384    // K buf B [128][64]u16   16384 B
#define PSA_OFF  32768    // P buf A [128][136]u16  34816 B
#define PSB_OFF  67584    // P buf B [128][136]u16  34816 B
#define LP_OFF   102400   // lpart [128][2] float    1024 B
#define YS_OFF   0        // epilogue ys [64][520]u16  66560 B (overlays Ks/PsA)
#define SMEM3    103424

#define SHIFT_C 20.0f     // softmax constant shift (overflow guard; result-invariant)

__global__ __launch_bounds__(1024, 4) void attn_mfma(
        const u16* __restrict__ Qb, const u16* __restrict__ Kb,
        const u16* __restrict__ xbfw, const void* __restrict__ xin,
        const int* __restrict__ flagp,
        const u16* __restrict__ vwb, const float* __restrict__ vbf,
        const float* __restrict__ gf, void* __restrict__ outv) {
    __shared__ __align__(16) char smem[SMEM3];
    char* KsA = smem + KSA_OFF;
    char* KsB = smem + KSB_OFF;
    u16* PsA = (u16*)(smem + PSA_OFF);
    u16* PsB = (u16*)(smem + PSB_OFF);
    u16* ys  = (u16*)(smem + YS_OFF);
    float* lpart = (float*)(smem + LP_OFF);

    const u16*   xb = (const u16*)xin;
    const float* xf = (const float*)xin;
    const int fl = *flagp;
    const u16* xb16 = fl ? (const u16*)xin : xbfw;   // bf16 view of x

    const int t = threadIdx.x;
    const int wv = t >> 6;            // 0..15
    const int lane = t & 63;
    const int L = lane & 15;
    const int q = lane >> 4;
    const int l31 = lane & 31;        // 32-row index for 32x32 MFMA operands
    const int q5 = lane >> 5;         // k-half for 32x32 MFMA operands
    const int rt = wv & 7;            // i-subtile (16 rows each, 128 total)
    const int h2 = wv >> 3;           // j-half (64-wide) of the 128-j tile

    // XCD-bijective remap: batch b pinned to XCD b (256 blocks, 256%8==0).
    const int gid  = blockIdx.y * 32 + blockIdx.x;
    const int ngid = (gid & 7) * 32 + (gid >> 3);
    const int b  = ngid >> 5;
    const int i0 = (ngid & 31) * 128;

    // Q fragments for this wave's 16 S-rows (i = i0 + 16rt + L)
    const u16* qp = Qb + ((size_t)b * N_ + i0 + 16 * rt + L) * 64;
    bf16x8 qf0 = *(const bf16x8*)(qp + 8 * q);
    bf16x8 qf1 = *(const bf16x8*)(qp + 32 + 8 * q);

    // per-lane partial row sums of exp(S - SHIFT_C); lane row i = 16rt+4q+r
    float lsum[4];
#pragma unroll
    for (int r = 0; r < 4; ++r) lsum[r] = 0.f;

    // accw[nt]: 32x32 D tile — c = 32wv + (reg&3)+8*(reg>>2)+4*q5, i = 32nt+l31
    f32x16 accw[4];
#pragma unroll
    for (int a = 0; a < 4; ++a) accw[a] = (f32x16)(0.f);

    // K staging: wave w stages rows 8w..8w+7 with ONE glds16 (64 lanes x 16B = 1KB).
    const int lane8 = lane >> 3;      // 0..7 = row within wave's 8-row slab
    const int kofs = (8 * wv + lane8) * 128 + ((((lane & 7) ^ lane8)) << 4);
    const char* ksrc0 = (const char*)Kb + ((size_t)b * N_) * 128 + kofs;
    char* kdstA = KsA + wv * 1024;
    char* kdstB = KsB + wv * 1024;
    // K read offsets (swizzled, XOR within the 128-B row — R12 lesson)
    const int swzL = (L & 7) << 4;
    const int krd0 = L * 128 + ((16 * q) ^ swzL);
    const int krd1 = L * 128 + ((64 + 16 * q) ^ swzL);

    // x A-operand base for 32x32x16 PV: row c = 32wv + l31, k-half q5
    const u16* xrow32 = xb16 + ((size_t)(b * C_ + 32 * wv + l31)) * N_ + 8 * q5;

    auto stageK = [&](int jt) {   // stage K tile jt -> Ks[jt&1] (async, 0 regs)
        glds16(ksrc0 + (size_t)jt * 16384, (jt & 1) ? kdstB : kdstA);
    };

    // p_compute in h-PAIRS: sv[2] live, exp issued early. (16x16x32, unchanged)
    auto p_compute = [&](int jt) {
        const char* kcur = (jt & 1) ? KsB : KsA;
        u16* psw = (jt & 1) ? PsB : PsA;
#pragma unroll
        for (int hp = 0; hp < 2; ++hp) {
            f32x4 sv[2];
#pragma unroll
            for (int hh = 0; hh < 2; ++hh) {
                int h = hp * 2 + hh;
                const char* kr = kcur + (64 * h2 + 16 * h) * 128;
                bf16x8 k0 = *(const bf16x8*)(kr + krd0);
                bf16x8 k1 = *(const bf16x8*)(kr + krd1);
                f32x4 z = {0.f, 0.f, 0.f, 0.f};
                z = __builtin_amdgcn_mfma_f32_16x16x32_bf16(qf0, k0, z, 0, 0, 0);
                z = __builtin_amdgcn_mfma_f32_16x16x32_bf16(qf1, k1, z, 0, 0, 0);
                sv[hh] = z;
            }
#pragma unroll
            for (int hh = 0; hh < 2; ++hh) {
                int h = hp * 2 + hh;
#pragma unroll
                for (int r = 0; r < 4; ++r) {
                    float p = __expf(sv[hh][r] - SHIFT_C);   // unnormalized
                    lsum[r] += p;
                    psw[(16 * rt + 4 * q + r) * 136 + 64 * h2 + 16 * h + L] = f2b(p);
                }
            }
        }
    };

    // PV on 32x32x16: per k32-pass 2 af + 8 pb + 8 MFMA (2x FLOP/instr vs 16x16).
    auto pv_step = [&](int jtp) {
        const u16* psr = (jtp & 1) ? PsB : PsA;
        const int j0pv = jtp << 7;
#pragma unroll
        for (int ks2 = 0; ks2 < 4; ++ks2) {
            bf16x8 afa = *(const bf16x8*)(xrow32 + j0pv + 32 * ks2);
            bf16x8 afb = *(const bf16x8*)(xrow32 + j0pv + 32 * ks2 + 16);
            __builtin_amdgcn_s_setprio(1);
#pragma unroll
            for (int nt = 0; nt < 4; ++nt) {
                bf16x8 pba = *(const bf16x8*)(psr + (32 * nt + l31) * 136
                                              + 32 * ks2 + 8 * q5);
                accw[nt] = __builtin_amdgcn_mfma_f32_32x32x16_bf16(
                    afa, pba, accw[nt], 0, 0, 0);
            }
#pragma unroll
            for (int nt = 0; nt < 4; ++nt) {
                bf16x8 pbb = *(const bf16x8*)(psr + (32 * nt + l31) * 136
                                              + 32 * ks2 + 16 + 8 * q5);
                accw[nt] = __builtin_amdgcn_mfma_f32_32x32x16_bf16(
                    afb, pbb, accw[nt], 0, 0, 0);
            }
            __builtin_amdgcn_s_setprio(0);
        }
    };

    // prologue: stage K0, K1 async; barrier drains both.
    stageK(0);
    stageK(1);
    __syncthreads();
    p_compute(0);

    for (int jt = 1; jt < 32; ++jt) {
        __syncthreads();   // all waves done p_compute(jt-1) & pv_step(jt-2)
        if (jt < 31) stageK(jt + 1);   // async; covered by p_compute below
        p_compute(jt);
        pv_step(jt - 1);
    }
    __syncthreads();       // P(31) visibility across waves
    pv_step(31);

    // ---- finalize l: reduce own-row partials over L lanes, combine j-halves -------
#pragma unroll
    for (int r = 0; r < 4; ++r) {
#pragma unroll
        for (int off = 8; off > 0; off >>= 1)
            lsum[r] += __shfl_xor(lsum[r], off, 64);
    }
    if (L == 0) {
#pragma unroll
        for (int r = 0; r < 4; ++r)
            lpart[(16 * rt + 4 * q + r) * 2 + h2] = lsum[r];
    }
    __syncthreads();   // lpart visible; all Ps/Ks reads done (ys overlay safe)

    float fi2[4];
#pragma unroll
    for (int nt = 0; nt < 4; ++nt) {
        int i = 32 * nt + l31;
        fi2[nt] = 1.0f / (lpart[i * 2] + lpart[i * 2 + 1]);
    }

    // pack accw -> bf16 (scaled by 1/l); frees the 64 acc AGPRs for the epilogue z.
    // value (nt,reg): y[c = 32wv + (reg&3)+8*(reg>>2)+4*q5][i = 32nt + l31]
    u16 pk2[4][16];
#pragma unroll
    for (int nt = 0; nt < 4; ++nt)
#pragma unroll
        for (int rg = 0; rg < 16; ++rg)
            pk2[nt][rg] = f2b(accw[nt][rg] * fi2[nt]);

    // ---- fused epilogue: z = vw @ y, out = gamma*(z+vb) + x, two i64 halves -------
    const float gma = gf[0];
#pragma unroll
    for (int ih = 0; ih < 2; ++ih) {
        if (ih) __syncthreads();   // previous half's ys reads complete
        // write this half's y: nt = 2ih, 2ih+1 -> ys rows 32*(nt&1)+l31
#pragma unroll
        for (int nth = 0; nth < 2; ++nth) {
            int nt = ih * 2 + nth;
#pragma unroll
            for (int rg = 0; rg < 16; ++rg) {
                int cr = (rg & 3) + 8 * (rg >> 2) + 4 * q5;
                ys[(32 * nth + l31) * 520 + 32 * wv + cr] = pk2[nt][rg];
            }
        }
        __syncthreads();

        f32x4 z[2][4];
#pragma unroll
        for (int a = 0; a < 2; ++a)
#pragma unroll
            for (int nb = 0; nb < 4; ++nb) z[a][nb] = (f32x4){0.f, 0.f, 0.f, 0.f};

#pragma unroll 1
        for (int kc = 0; kc < 8; ++kc) {
#pragma unroll
            for (int nn = 0; nn < 4; ++nn) {
                const u16* yr = ys + (16 * nn + L) * 520 + kc * 64;
                bf16x8 yb0 = *(const bf16x8*)(yr + 8 * q);
                bf16x8 yb1 = *(const bf16x8*)(yr + 32 + 8 * q);
#pragma unroll
                for (int mtp = 0; mtp < 2; ++mtp) {
                    int crow = 32 * wv + 16 * mtp + L;
                    const u16* wp = vwb + (size_t)crow * C_ + kc * 64;
                    bf16x8 a0 = *(const bf16x8*)(wp + 8 * q);
                    bf16x8 a1 = *(const bf16x8*)(wp + 32 + 8 * q);
                    z[mtp][nn] = __builtin_amdgcn_mfma_f32_16x16x32_bf16(
                        a0, yb0, z[mtp][nn], 0, 0, 0);
                    z[mtp][nn] = __builtin_amdgcn_mfma_f32_16x16x32_bf16(
                        a1, yb1, z[mtp][nn], 0, 0, 0);
                }
            }
        }
        // store this i-half
#pragma unroll
        for (int mtp = 0; mtp < 2; ++mtp)
#pragma unroll
            for (int nn = 0; nn < 4; ++nn)
#pragma unroll
                for (int r = 0; r < 4; ++r) {
                    int cp = 32 * wv + 16 * mtp + 4 * q + r;
                    int ii = i0 + ih * 64 + 16 * nn + L;
                    size_t oi = ((size_t)(b * C_ + cp)) * N_ + ii;
                    float val = gma * (z[mtp][nn][r] + vbf[cp]);
                    if (fl) ((u16*)outv)[oi] = f2b(val + b2f(xb[oi]));
                    else    ((float*)outv)[oi] = val + xf[oi];
                }
    }
}

extern "C" void kernel_launch(void* const* d_in, const int* in_sizes, int n_in,
                              void* d_out, int out_size, void* d_ws, size_t ws_size,
                              hipStream_t stream) {
    const void* x  = d_in[0];
    const void* qw = d_in[1];
    const void* qb = d_in[2];
    const void* kw = d_in[3];
    const void* kb = d_in[4];
    const void* vw = d_in[5];
    const void* vb = d_in[6];
    const void* gm = d_in[7];

    char* ws = (char*)d_ws;
    int*   flag = (int*)(ws + 0);
    float* gf   = (float*)(ws + 16);
    float* bcat = (float*)(ws + 32);
    float* vbf  = (float*)(ws + 544);
    float* wt   = (float*)(ws + 2592);
    u16*   Qb   = (u16*)(ws + 264736);
    u16*   Kb   = (u16*)(ws + 4459040);
    u16*   vwb  = (u16*)(ws + 8653344);
    u16*   xbf  = (u16*)(ws + 9177632);   // total ws use: 42,732,064 B

    detect_dtype<<<dim3(1), dim3(256), 0, stream>>>((const u16*)x, flag);
    prep_params<<<dim3(256), dim3(256), 0, stream>>>(
        qw, qb, kw, kb, vb, gm, vw, flag, wt, bcat, vbf, gf, vwb);
    proj_qk<<<dim3(2, 64, 8), dim3(256), 0, stream>>>(x, flag, wt, bcat, Qb, Kb, xbf);
    attn_mfma<<<dim3(32, 8), dim3(1024), 0, stream>>>(
        Qb, Kb, xbf, x, flag, vwb, vbf, gf, d_out);
}